// Round 15
// baseline (1305.877 us; speedup 1.0000x reference)
//
#include <hip/hip_runtime.h>

#define B_ 8192
#define D_ 1024
#define K_ 4096
#define H_ 8

#define BE 256   // codebook rows per block
#define BR 128   // resid rows per block
#define BK 32
#define NBLK 32        // 128-codeword argmin blocks per row
#define TOPB 3         // candidates kept per block
#define NCAND 8        // exact-rescored candidates per row

typedef __attribute__((ext_vector_type(8))) short short8v;
typedef __attribute__((ext_vector_type(4))) float f32x4;

#define FINF 3.4e38f
#define IBIG 0x7fffffff

__device__ __forceinline__ void amin(float& v, int& i, float v2, int i2) {
    if (v2 < v || (v2 == v && i2 < i)) { v = v2; i = i2; }
}

__device__ __forceinline__ unsigned short f2bf_rn(float x) {
    unsigned int u = __float_as_uint(x);
    unsigned int r = (u + 0x7fffu + ((u >> 16) & 1u)) >> 16;
    return (unsigned short)r;
}

__device__ __forceinline__ void gload16(const unsigned short* g, unsigned short* l) {
    __builtin_amdgcn_global_load_lds(
        (const __attribute__((address_space(1))) void*)g,
        (__attribute__((address_space(3))) void*)l, 16, 0, 0);
}

// ---------------------------------------------------------------------------
// Per head: codebook row -> bf16 hi + ee[k] = ||E_k||^2 (fused single read)
// ---------------------------------------------------------------------------
__global__ __launch_bounds__(256) void cbconv_kernel(const float* __restrict__ E,
                                                     unsigned short* __restrict__ hi,
                                                     float* __restrict__ eeh) {
    const int row = blockIdx.x;
    const int t = threadIdx.x;
    float4 v = reinterpret_cast<const float4*>(E + (size_t)row * D_)[t];
    ushort4 h;
    h.x = f2bf_rn(v.x); h.y = f2bf_rn(v.y);
    h.z = f2bf_rn(v.z); h.w = f2bf_rn(v.w);
    reinterpret_cast<ushort4*>(hi + (size_t)row * D_)[t] = h;
    float s = v.x * v.x + v.y * v.y + v.z * v.z + v.w * v.w;
    #pragma unroll
    for (int m = 1; m < 64; m <<= 1) s += __shfl_xor(s, m);
    __shared__ float ls[4];
    if ((t & 63) == 0) ls[t >> 6] = s;
    __syncthreads();
    if (t == 0) eeh[row] = (ls[0] + ls[1]) + (ls[2] + ls[3]);
}

// ---------------------------------------------------------------------------
// resid = x ; rr = ||x||^2 ; resid bf16 hi
// ---------------------------------------------------------------------------
__global__ __launch_bounds__(256) void init_kernel(const float* __restrict__ x,
                                                   float* __restrict__ resid,
                                                   float* __restrict__ rr,
                                                   unsigned short* __restrict__ rhi) {
    const int b = blockIdx.x;
    const int t = threadIdx.x;
    float4 v = reinterpret_cast<const float4*>(x + (size_t)b * D_)[t];
    reinterpret_cast<float4*>(resid + (size_t)b * D_)[t] = v;
    ushort4 h;
    h.x = f2bf_rn(v.x); h.y = f2bf_rn(v.y);
    h.z = f2bf_rn(v.z); h.w = f2bf_rn(v.w);
    reinterpret_cast<ushort4*>(rhi + (size_t)b * D_)[t] = h;
    float s = v.x * v.x + v.y * v.y + v.z * v.z + v.w * v.w;
    #pragma unroll
    for (int m = 1; m < 64; m <<= 1) s += __shfl_xor(s, m);
    __shared__ float ls[4];
    if ((t & 63) == 0) ls[t >> 6] = s;
    __syncthreads();
    if (t == 0) rr[b] = (ls[0] + ls[1]) + (ls[2] + ls[3]);
}

// ---------------------------------------------------------------------------
// 256E x 128R swapped-operand bf16 MFMA score + lane-local TOP-3 argmin.
//   4 waves = 2E x 2R; per-wave acc[8][4] -> 32 MFMA from 12 b128 reads/iter
//   (0.5625 KB LDS/MFMA vs 0.75 in the 128x128 variant).
//   BK=32 keeps 64-B rows (free 2-way bank alias). LDS 24 KB.
//   C layout: E-row = i*16 + (l>>4)*4 + reg ; resid col = j*16 + (l&15).
// Rank value = ee[k] - 2*dot (rv const per row; exact rescore adds it later).
// XCD decode: each XCD owns 2 E-tiles (2 MB bf16, L2-resident).
// ---------------------------------------------------------------------------
__global__ __launch_bounds__(256, 2) void score_mfma_kernel(
    const unsigned short* __restrict__ Ch,   // codebook bf16 [K][D]
    const unsigned short* __restrict__ Rh,   // resid bf16 [B][D]
    const float* __restrict__ ee,
    float* __restrict__ pval, int* __restrict__ pidx) {
    __shared__ unsigned short ldsE[BE][BK];   // 16 KB
    __shared__ unsigned short ldsR[BR][BK];   // 8 KB

    const int tid = threadIdx.x;
    // --- XCD-aware decode (bijective: 1024 blocks, 1024 % 8 == 0)
    const int bid = blockIdx.x;
    const int xcd = bid & 7;
    const int r_  = bid >> 3;                // 0..127
    const int bx  = (xcd << 1) | (r_ & 1);   // E tile 0..15
    const int by  = r_ >> 1;                 // resid tile 0..63
    const int be0 = bx * BE;
    const int br0 = by * BR;

    f32x4 acc[8][4];
    #pragma unroll
    for (int i = 0; i < 8; ++i)
        #pragma unroll
        for (int j = 0; j < 4; ++j)
            #pragma unroll
            for (int r = 0; r < 4; ++r) acc[i][j][r] = 0.f;

    // staging: thread t covers row (t>>2)+c*64, ushorts (t&3)*8 .. +7
    const int srow = tid >> 2;          // 0..63
    const int sch  = (tid & 3) * 8;
    const size_t rstep = (size_t)64 * D_;
    const unsigned short* pE = Ch + (size_t)(be0 + srow) * D_ + sch;
    const unsigned short* pR = Rh + (size_t)(br0 + srow) * D_ + sch;

    const int l  = tid & 63;
    const int w  = tid >> 6;
    const int wE = w >> 1;           // 0..1 : E half (128 rows)
    const int wR = w & 1;            // 0..1 : resid half (64 rows)
    const int fr = l & 15;
    const int k8 = (l >> 4) * 8;

    for (int d0 = 0; d0 < D_; d0 += BK) {
        __syncthreads();
        #pragma unroll
        for (int c = 0; c < 4; ++c)
            gload16(pE + c * rstep + d0, &ldsE[srow + c * 64][sch]);
        #pragma unroll
        for (int c = 0; c < 2; ++c)
            gload16(pR + c * rstep + d0, &ldsR[srow + c * 64][sch]);
        __syncthreads();

        short8v af[8], bf[4];
        #pragma unroll
        for (int i = 0; i < 8; ++i)
            af[i] = *reinterpret_cast<const short8v*>(&ldsE[wE * 128 + i * 16 + fr][k8]);
        #pragma unroll
        for (int j = 0; j < 4; ++j)
            bf[j] = *reinterpret_cast<const short8v*>(&ldsR[wR * 64 + j * 16 + fr][k8]);
        #pragma unroll
        for (int i = 0; i < 8; ++i)
            #pragma unroll
            for (int j = 0; j < 4; ++j)
                acc[i][j] = __builtin_amdgcn_mfma_f32_16x16x32_bf16(af[i], bf[j], acc[i][j], 0, 0, 0);
    }

    // ---- epilogue: per-resid-row top-3 over this wave's 128 E-rows ----
    const int g4 = (l >> 4) * 4;
    float ev[8][4];
    int ecd[8][4];
    #pragma unroll
    for (int i = 0; i < 8; ++i)
        #pragma unroll
        for (int r = 0; r < 4; ++r) {
            ecd[i][r] = be0 + wE * 128 + i * 16 + g4 + r;
            ev[i][r] = ee[ecd[i][r]];
        }
    const int eblk = bx * 2 + wE;   // 128-E-row block id 0..31

    #define INS3(v, c) do {                                         \
        const float _v = (v); const int _c = (c);                   \
        if (_v < b1 || (_v == b1 && _c < i1)) {                     \
            b3 = b2; i3 = i2; b2 = b1; i2 = i1; b1 = _v; i1 = _c;   \
        } else if (_v < b2 || (_v == b2 && _c < i2)) {              \
            b3 = b2; i3 = i2; b2 = _v; i2 = _c;                     \
        } else if (_v < b3 || (_v == b3 && _c < i3)) {              \
            b3 = _v; i3 = _c;                                       \
        }                                                           \
    } while (0)

    #pragma unroll
    for (int j = 0; j < 4; ++j) {
        const int rrow = br0 + wR * 64 + j * 16 + fr;
        float b1 = FINF, b2 = FINF, b3 = FINF;
        int i1 = IBIG, i2 = IBIG, i3 = IBIG;
        #pragma unroll
        for (int i = 0; i < 8; ++i)
            #pragma unroll
            for (int r = 0; r < 4; ++r) {
                const float s = fmaf(-2.0f, acc[i][j][r], ev[i][r]);
                INS3(s, ecd[i][r]);
            }
        // merge sorted triples across the 4 lanes sharing fr (xor 16, 32)
        #pragma unroll
        for (int m = 16; m < 64; m <<= 1) {
            const float o1 = __shfl_xor(b1, m); const int oi1 = __shfl_xor(i1, m);
            const float o2 = __shfl_xor(b2, m); const int oi2 = __shfl_xor(i2, m);
            const float o3 = __shfl_xor(b3, m); const int oi3 = __shfl_xor(i3, m);
            INS3(o1, oi1); INS3(o2, oi2); INS3(o3, oi3);
        }
        if ((l >> 4) == 0) {
            const size_t base = ((size_t)rrow * NBLK + eblk) * TOPB;
            pval[base] = b1;     pidx[base] = i1;
            pval[base + 1] = b2; pidx[base + 1] = i2;
            pval[base + 2] = b3; pidx[base + 2] = i3;
        }
    }
    #undef INS3
}

// ---------------------------------------------------------------------------
// Wave-per-row update: 4 rows per block, no LDS. Top-NCAND extraction from
// 96 partials (lane l<32 owns block l), EXACT fp32 rescore, argmin (value
// then lowest index), exact resid update + bf16 re-split. Last head also
// emits quantized = x - resid_new (register-resident).
// ---------------------------------------------------------------------------
__global__ __launch_bounds__(256) void update_kernel(
    float* __restrict__ resid,
    const float* __restrict__ E,
    const float* __restrict__ ee,
    const float* __restrict__ pval,
    const int* __restrict__ pidx,
    float* __restrict__ rr,
    float* __restrict__ codes,
    unsigned short* __restrict__ rhi,
    const float* __restrict__ x,
    float* __restrict__ quant,
    int h) {
    const int w = threadIdx.x >> 6;
    const int l = threadIdx.x & 63;
    const int b = blockIdx.x * 4 + w;

    // --- candidate extraction: lane l (<NBLK) owns the 3 partials of block l
    float v0 = FINF, v1 = FINF, v2 = FINF;
    int i0 = IBIG, i1 = IBIG, i2 = IBIG;
    if (l < NBLK) {
        const size_t pbase = ((size_t)b * NBLK + l) * TOPB;
        v0 = pval[pbase];     i0 = pidx[pbase];
        v1 = pval[pbase + 1]; i1 = pidx[pbase + 1];
        v2 = pval[pbase + 2]; i2 = pidx[pbase + 2];
    }
    int cand[NCAND];
    #pragma unroll
    for (int r = 0; r < NCAND; ++r) {
        float av = v0; int ai = i0;
        amin(av, ai, v1, i1);
        amin(av, ai, v2, i2);
        #pragma unroll
        for (int m = 1; m < 64; m <<= 1) {
            float ov = __shfl_xor(av, m);
            int oi = __shfl_xor(ai, m);
            amin(av, ai, ov, oi);
        }
        if (ai == i0) v0 = FINF;   // consume (indices unique across partials)
        if (ai == i1) v1 = FINF;
        if (ai == i2) v2 = FINF;
        cand[r] = ai;              // uniform across the wave
    }

    // --- resid row into registers (reused for rescore AND update)
    const float4* r4row = reinterpret_cast<const float4*>(resid + (size_t)b * D_);
    float4 rx[4];
    #pragma unroll
    for (int q = 0; q < 4; ++q) rx[q] = r4row[q * 64 + l];

    // --- exact fp32 rescore of the NCAND candidates
    float dots[NCAND];
    #pragma unroll
    for (int c = 0; c < NCAND; ++c) {
        const float4* e4 = reinterpret_cast<const float4*>(E + (size_t)cand[c] * D_);
        float dot = 0.f;
        #pragma unroll
        for (int q = 0; q < 4; ++q) {
            float4 e = e4[q * 64 + l];
            dot = fmaf(rx[q].x, e.x, dot);
            dot = fmaf(rx[q].y, e.y, dot);
            dot = fmaf(rx[q].z, e.z, dot);
            dot = fmaf(rx[q].w, e.w, dot);
        }
        #pragma unroll
        for (int m = 1; m < 64; m <<= 1) dot += __shfl_xor(dot, m);
        dots[c] = dot;             // uniform
    }

    // --- final selection (uniform computation on all lanes)
    const float rv = rr[b];
    float bv = FINF; int bi = IBIG;
    #pragma unroll
    for (int c = 0; c < NCAND; ++c) {
        const float s = (rv - 2.0f * dots[c]) + ee[cand[c]];
        amin(bv, bi, s, cand[c]);
    }
    if (l == 0) codes[(size_t)b * H_ + h] = (float)bi;

    // --- exact fp32 residual update (order matches reference elementwise)
    const float4* q4 = reinterpret_cast<const float4*>(E + (size_t)bi * D_);
    float4* r4w = reinterpret_cast<float4*>(resid + (size_t)b * D_);
    ushort4* h4w = reinterpret_cast<ushort4*>(rhi + (size_t)b * D_);
    float nrm = 0.f;
    #pragma unroll
    for (int q = 0; q < 4; ++q) {
        float4 qv = q4[q * 64 + l];
        float4 r = rx[q];
        r.x -= qv.x; r.y -= qv.y; r.z -= qv.z; r.w -= qv.w;
        rx[q] = r;
        r4w[q * 64 + l] = r;
        ushort4 hh;
        hh.x = f2bf_rn(r.x); hh.y = f2bf_rn(r.y);
        hh.z = f2bf_rn(r.z); hh.w = f2bf_rn(r.w);
        h4w[q * 64 + l] = hh;
        nrm += r.x * r.x + r.y * r.y + r.z * r.z + r.w * r.w;
    }
    #pragma unroll
    for (int m = 1; m < 64; m <<= 1) nrm += __shfl_xor(nrm, m);
    if (l == 0) rr[b] = nrm;

    // --- last head: quantized = x - resid_final (reconstruction err ~1e-5)
    if (h == H_ - 1) {
        const float4* x4 = reinterpret_cast<const float4*>(x + (size_t)b * D_);
        float4* o4 = reinterpret_cast<float4*>(quant + (size_t)b * D_);
        #pragma unroll
        for (int q = 0; q < 4; ++q) {
            float4 xv = x4[q * 64 + l];
            float4 o;
            o.x = xv.x - rx[q].x; o.y = xv.y - rx[q].y;
            o.z = xv.z - rx[q].z; o.w = xv.w - rx[q].w;
            o4[q * 64 + l] = o;
        }
    }
}

// ---------------------------------------------------------------------------
extern "C" void kernel_launch(void* const* d_in, const int* in_sizes, int n_in,
                              void* d_out, int out_size, void* d_ws, size_t ws_size,
                              hipStream_t stream) {
    const float* x  = (const float*)d_in[0];   // [B][1][D]
    const float* cb = (const float*)d_in[1];   // [H][K][D]
    float* out = (float*)d_out;
    float* quant = out;                          // [B][D]
    float* codes = out + (size_t)B_ * D_;        // [B][H] as float

    char* ws = (char*)d_ws;
    size_t off = 0;
    float* resid = (float*)(ws + off); off += (size_t)B_ * D_ * 4;              // 32 MB
    float* rr    = (float*)(ws + off); off += (size_t)B_ * 4;
    float* ee    = (float*)(ws + off); off += (size_t)H_ * K_ * 4;              // 128 KB
    float* pval  = (float*)(ws + off); off += (size_t)B_ * NBLK * TOPB * 4;     // 3 MB
    int*   pidx  = (int*)  (ws + off); off += (size_t)B_ * NBLK * TOPB * 4;     // 3 MB
    unsigned short* rhi = (unsigned short*)(ws + off); off += (size_t)B_ * D_ * 2;  // 16 MB
    unsigned short* chi = (unsigned short*)(ws + off); off += (size_t)K_ * D_ * 2;  // 8 MB

    hipLaunchKernelGGL(init_kernel, dim3(B_), dim3(256), 0, stream, x, resid, rr, rhi);

    for (int h = 0; h < H_; ++h) {
        const float* E  = cb + (size_t)h * K_ * D_;
        float* eh = ee + (size_t)h * K_;
        hipLaunchKernelGGL(cbconv_kernel, dim3(K_), dim3(256), 0, stream, E, chi, eh);
        hipLaunchKernelGGL(score_mfma_kernel, dim3((K_ / BE) * (B_ / BR)), dim3(256),
                           0, stream, chi, rhi, eh, pval, pidx);
        hipLaunchKernelGGL(update_kernel, dim3(B_ / 4), dim3(256), 0, stream,
                           resid, E, eh, pval, pidx, rr, codes, rhi, x, quant, h);
    }
}

// Round 16
// 1153.555 us; speedup vs baseline: 1.1320x; 1.1320x over previous
//
#include <hip/hip_runtime.h>

#define B_ 8192
#define D_ 1024
#define K_ 4096
#define H_ 8

#define BM 128   // resid rows per block (B operand)
#define BN 128   // codebook rows per block (A operand)
#define BK 32
#define NBLK 64        // 64-codeword argmin blocks per row
#define NCAND 6        // exact-rescored candidates per row

typedef __attribute__((ext_vector_type(8))) short short8v;
typedef __attribute__((ext_vector_type(4))) float f32x4;

#define FINF 3.4e38f
#define IBIG 0x7fffffff

__device__ __forceinline__ void amin(float& v, int& i, float v2, int i2) {
    if (v2 < v || (v2 == v && i2 < i)) { v = v2; i = i2; }
}

__device__ __forceinline__ unsigned short f2bf_rn(float x) {
    unsigned int u = __float_as_uint(x);
    unsigned int r = (u + 0x7fffu + ((u >> 16) & 1u)) >> 16;
    return (unsigned short)r;
}

__device__ __forceinline__ void gload16(const unsigned short* g, unsigned short* l) {
    __builtin_amdgcn_global_load_lds(
        (const __attribute__((address_space(1))) void*)g,
        (__attribute__((address_space(3))) void*)l, 16, 0, 0);
}

// ---------------------------------------------------------------------------
// Per head: codebook row -> bf16 hi + ee[k] = ||E_k||^2 (fused single read)
// ---------------------------------------------------------------------------
__global__ __launch_bounds__(256) void cbconv_kernel(const float* __restrict__ E,
                                                     unsigned short* __restrict__ hi,
                                                     float* __restrict__ eeh) {
    const int row = blockIdx.x;
    const int t = threadIdx.x;
    float4 v = reinterpret_cast<const float4*>(E + (size_t)row * D_)[t];
    ushort4 h;
    h.x = f2bf_rn(v.x); h.y = f2bf_rn(v.y);
    h.z = f2bf_rn(v.z); h.w = f2bf_rn(v.w);
    reinterpret_cast<ushort4*>(hi + (size_t)row * D_)[t] = h;
    float s = v.x * v.x + v.y * v.y + v.z * v.z + v.w * v.w;
    #pragma unroll
    for (int m = 1; m < 64; m <<= 1) s += __shfl_xor(s, m);
    __shared__ float ls[4];
    if ((t & 63) == 0) ls[t >> 6] = s;
    __syncthreads();
    if (t == 0) eeh[row] = (ls[0] + ls[1]) + (ls[2] + ls[3]);
}

// ---------------------------------------------------------------------------
// resid = x ; rr = ||x||^2 ; resid bf16 hi
// ---------------------------------------------------------------------------
__global__ __launch_bounds__(256) void init_kernel(const float* __restrict__ x,
                                                   float* __restrict__ resid,
                                                   float* __restrict__ rr,
                                                   unsigned short* __restrict__ rhi) {
    const int b = blockIdx.x;
    const int t = threadIdx.x;
    float4 v = reinterpret_cast<const float4*>(x + (size_t)b * D_)[t];
    reinterpret_cast<float4*>(resid + (size_t)b * D_)[t] = v;
    ushort4 h;
    h.x = f2bf_rn(v.x); h.y = f2bf_rn(v.y);
    h.z = f2bf_rn(v.z); h.w = f2bf_rn(v.w);
    reinterpret_cast<ushort4*>(rhi + (size_t)b * D_)[t] = h;
    float s = v.x * v.x + v.y * v.y + v.z * v.z + v.w * v.w;
    #pragma unroll
    for (int m = 1; m < 64; m <<= 1) s += __shfl_xor(s, m);
    __shared__ float ls[4];
    if ((t & 63) == 0) ls[t >> 6] = s;
    __syncthreads();
    if (t == 0) rr[b] = (ls[0] + ls[1]) + (ls[2] + ls[3]);
}

// ---------------------------------------------------------------------------
// Swapped-operand bf16 MFMA approx score + lane-local TOP-2 argmin.
//   A = codebook (E rows), B = resid rows
//   C layout: row = E-row = i*16 + (l>>4)*4 + reg ; col = resid = j*16 + (l&15)
// => each lane holds 16 E-candidates for its resid row in REGISTERS;
//    per-row top-2 = local amins + 2-stage cross-lane merge (masks 16,32).
// Rank value = ee[k] - 2*dot (rv const per row; exact rescore adds it later).
// XCD-aware 1-D grid decode: bid&7 = XCD; each XCD owns a 4-tile codebook
// octant (1 MB, L2-resident) and walks resid tiles with 4-block reuse.
// (verified best: 104.9 us/head, round 12)
// ---------------------------------------------------------------------------
__global__ __launch_bounds__(256) void score_mfma_kernel(
    const unsigned short* __restrict__ Ch,   // codebook bf16 [K][D]
    const unsigned short* __restrict__ Rh,   // resid bf16 [B][D]
    const float* __restrict__ ee,
    float* __restrict__ pval, int* __restrict__ pidx) {
    __shared__ unsigned short lds[2][128][BK];   // [0]=codebook, [1]=resid : 16 KB

    const int tid = threadIdx.x;
    // --- XCD-aware decode (bijective: 2048 blocks, 2048 % 8 == 0)
    const int bid = blockIdx.x;
    const int xcd = bid & 7;
    const int r_  = bid >> 3;           // 0..255
    const int bx  = (xcd << 2) | (r_ & 3);   // codebook tile 0..31
    const int by  = r_ >> 2;                 // resid tile 0..63
    const int be0 = bx * BN;   // codebook block base
    const int br0 = by * BM;   // resid block base

    f32x4 acc[4][4];   // acc[i][j]: i = E subtile, j = resid subtile
    #pragma unroll
    for (int i = 0; i < 4; ++i)
        #pragma unroll
        for (int j = 0; j < 4; ++j)
            #pragma unroll
            for (int r = 0; r < 4; ++r) acc[i][j][r] = 0.f;

    const int srow = tid >> 2;          // 0..63
    const int sch  = (tid & 3) * 8;
    const size_t rstep = (size_t)64 * D_;
    const unsigned short* pC = Ch + (size_t)(be0 + srow) * D_ + sch;
    const unsigned short* pR = Rh + (size_t)(br0 + srow) * D_ + sch;

    const int l  = tid & 63;
    const int w  = tid >> 6;
    const int wr = (w >> 1) * 64;    // wave E offset
    const int wc = (w & 1) * 64;     // wave resid offset
    const int fr = l & 15;
    const int k8 = (l >> 4) * 8;

    for (int d0 = 0; d0 < D_; d0 += BK) {
        __syncthreads();
        gload16(pC + d0,         &lds[0][srow][sch]);
        gload16(pC + rstep + d0, &lds[0][srow + 64][sch]);
        gload16(pR + d0,         &lds[1][srow][sch]);
        gload16(pR + rstep + d0, &lds[1][srow + 64][sch]);
        __syncthreads();

        short8v a_h[4], b_h[4];
        #pragma unroll
        for (int f = 0; f < 4; ++f) {
            a_h[f] = *reinterpret_cast<const short8v*>(&lds[0][wr + f * 16 + fr][k8]);
            b_h[f] = *reinterpret_cast<const short8v*>(&lds[1][wc + f * 16 + fr][k8]);
        }
        #pragma unroll
        for (int i = 0; i < 4; ++i)
            #pragma unroll
            for (int j = 0; j < 4; ++j)
                acc[i][j] = __builtin_amdgcn_mfma_f32_16x16x32_bf16(a_h[i], b_h[j], acc[i][j], 0, 0, 0);
    }

    // ---- epilogue: per-resid-row top-2 over this wave's 64 E-rows ----
    const int g4 = (l >> 4) * 4;
    float eb[4][4];
    int ec[4][4];
    #pragma unroll
    for (int i = 0; i < 4; ++i)
        #pragma unroll
        for (int r = 0; r < 4; ++r) {
            ec[i][r] = be0 + wr + i * 16 + g4 + r;
            eb[i][r] = ee[ec[i][r]];
        }
    const int eblk = bx * 2 + (w >> 1);   // 64-E-row block id 0..63

    #pragma unroll
    for (int j = 0; j < 4; ++j) {
        const int rrow = br0 + wc + j * 16 + fr;   // this lane's resid row
        float b1 = FINF; int i1 = IBIG;
        float b2 = FINF; int i2 = IBIG;
        #pragma unroll
        for (int i = 0; i < 4; ++i)
            #pragma unroll
            for (int r = 0; r < 4; ++r) {
                const float s = fmaf(-2.0f, acc[i][j][r], eb[i][r]);
                const int c = ec[i][r];
                const bool lt = (s < b1) || (s == b1 && c < i1);
                const float lv = lt ? b1 : s;
                const int   li = lt ? i1 : c;
                if (lt) { b1 = s; i1 = c; }
                amin(b2, i2, lv, li);
            }
        // merge top-2 pairs across the 4 lanes sharing (l&15)
        #pragma unroll
        for (int m = 16; m < 64; m <<= 1) {
            const float o1 = __shfl_xor(b1, m); const int oi1 = __shfl_xor(i1, m);
            const float o2 = __shfl_xor(b2, m); const int oi2 = __shfl_xor(i2, m);
            const bool lt = (o1 < b1) || (o1 == b1 && oi1 < i1);
            const float lv = lt ? b1 : o1;
            const int   li = lt ? i1 : oi1;
            if (lt) { b1 = o1; i1 = oi1; }
            amin(b2, i2, o2, oi2);
            amin(b2, i2, lv, li);
        }
        if ((l >> 4) == 0) {
            const size_t base = ((size_t)rrow * NBLK + eblk) * 2;
            pval[base] = b1;     pidx[base] = i1;
            pval[base + 1] = b2; pidx[base + 1] = i2;
        }
    }
}

// ---------------------------------------------------------------------------
// Wave-per-row update: 4 rows per 256-thread block, zero idle waves, no LDS.
// Per row: top-NCAND extraction from 128 partials, EXACT fp32 rescore of the
// candidates, argmin (value then lowest index), exact resid update + re-split.
// On the last head also emits quantized = x - resid_new (register-resident).
// ---------------------------------------------------------------------------
__global__ __launch_bounds__(256) void update_kernel(
    float* __restrict__ resid,
    const float* __restrict__ E,
    const float* __restrict__ ee,
    const float* __restrict__ pval,
    const int* __restrict__ pidx,
    float* __restrict__ rr,
    float* __restrict__ codes,
    unsigned short* __restrict__ rhi,
    const float* __restrict__ x,
    float* __restrict__ quant,
    int h) {
    const int w = threadIdx.x >> 6;
    const int l = threadIdx.x & 63;
    const int b = blockIdx.x * 4 + w;

    // --- candidate extraction: lane l owns the 2 partials of block l
    const size_t pbase = ((size_t)b * NBLK + l) * 2;
    float v0 = pval[pbase], v1 = pval[pbase + 1];
    int i0 = pidx[pbase], i1 = pidx[pbase + 1];
    int cand[NCAND];
    #pragma unroll
    for (int r = 0; r < NCAND; ++r) {
        float av = v0; int ai = i0;
        amin(av, ai, v1, i1);
        #pragma unroll
        for (int m = 1; m < 64; m <<= 1) {
            float ov = __shfl_xor(av, m);
            int oi = __shfl_xor(ai, m);
            amin(av, ai, ov, oi);
        }
        if (ai == i0) v0 = FINF;   // consume (indices unique across partials)
        if (ai == i1) v1 = FINF;
        cand[r] = ai;              // uniform across the wave
    }

    // --- resid row into registers (reused for rescore AND update)
    const float4* r4row = reinterpret_cast<const float4*>(resid + (size_t)b * D_);
    float4 rx[4];
    #pragma unroll
    for (int q = 0; q < 4; ++q) rx[q] = r4row[q * 64 + l];

    // --- exact fp32 rescore of the NCAND candidates
    float dots[NCAND];
    #pragma unroll
    for (int c = 0; c < NCAND; ++c) {
        const float4* e4 = reinterpret_cast<const float4*>(E + (size_t)cand[c] * D_);
        float dot = 0.f;
        #pragma unroll
        for (int q = 0; q < 4; ++q) {
            float4 e = e4[q * 64 + l];
            dot = fmaf(rx[q].x, e.x, dot);
            dot = fmaf(rx[q].y, e.y, dot);
            dot = fmaf(rx[q].z, e.z, dot);
            dot = fmaf(rx[q].w, e.w, dot);
        }
        #pragma unroll
        for (int m = 1; m < 64; m <<= 1) dot += __shfl_xor(dot, m);
        dots[c] = dot;             // uniform
    }

    // --- final selection (uniform computation on all lanes)
    const float rv = rr[b];
    float bv = FINF; int bi = IBIG;
    #pragma unroll
    for (int c = 0; c < NCAND; ++c) {
        const float s = (rv - 2.0f * dots[c]) + ee[cand[c]];
        amin(bv, bi, s, cand[c]);
    }
    if (l == 0) codes[(size_t)b * H_ + h] = (float)bi;

    // --- exact fp32 residual update (order matches reference elementwise)
    const float4* q4 = reinterpret_cast<const float4*>(E + (size_t)bi * D_);
    float4* r4w = reinterpret_cast<float4*>(resid + (size_t)b * D_);
    ushort4* h4w = reinterpret_cast<ushort4*>(rhi + (size_t)b * D_);
    float nrm = 0.f;
    #pragma unroll
    for (int q = 0; q < 4; ++q) {
        float4 qv = q4[q * 64 + l];
        float4 r = rx[q];
        r.x -= qv.x; r.y -= qv.y; r.z -= qv.z; r.w -= qv.w;
        rx[q] = r;
        r4w[q * 64 + l] = r;
        ushort4 hh;
        hh.x = f2bf_rn(r.x); hh.y = f2bf_rn(r.y);
        hh.z = f2bf_rn(r.z); hh.w = f2bf_rn(r.w);
        h4w[q * 64 + l] = hh;
        nrm += r.x * r.x + r.y * r.y + r.z * r.z + r.w * r.w;
    }
    #pragma unroll
    for (int m = 1; m < 64; m <<= 1) nrm += __shfl_xor(nrm, m);
    if (l == 0) rr[b] = nrm;

    // --- last head: quantized = x - resid_final (reconstruction error ~1e-5)
    if (h == H_ - 1) {
        const float4* x4 = reinterpret_cast<const float4*>(x + (size_t)b * D_);
        float4* o4 = reinterpret_cast<float4*>(quant + (size_t)b * D_);
        #pragma unroll
        for (int q = 0; q < 4; ++q) {
            float4 xv = x4[q * 64 + l];
            float4 o;
            o.x = xv.x - rx[q].x; o.y = xv.y - rx[q].y;
            o.z = xv.z - rx[q].z; o.w = xv.w - rx[q].w;
            o4[q * 64 + l] = o;
        }
    }
}

// ---------------------------------------------------------------------------
extern "C" void kernel_launch(void* const* d_in, const int* in_sizes, int n_in,
                              void* d_out, int out_size, void* d_ws, size_t ws_size,
                              hipStream_t stream) {
    const float* x  = (const float*)d_in[0];   // [B][1][D]
    const float* cb = (const float*)d_in[1];   // [H][K][D]
    float* out = (float*)d_out;
    float* quant = out;                          // [B][D]
    float* codes = out + (size_t)B_ * D_;        // [B][H] as float

    char* ws = (char*)d_ws;
    size_t off = 0;
    float* resid = (float*)(ws + off); off += (size_t)B_ * D_ * 4;          // 32 MB
    float* rr    = (float*)(ws + off); off += (size_t)B_ * 4;
    float* ee    = (float*)(ws + off); off += (size_t)H_ * K_ * 4;          // 128 KB
    float* pval  = (float*)(ws + off); off += (size_t)B_ * NBLK * 2 * 4;    // 4 MB
    int*   pidx  = (int*)  (ws + off); off += (size_t)B_ * NBLK * 2 * 4;    // 4 MB
    unsigned short* rhi = (unsigned short*)(ws + off); off += (size_t)B_ * D_ * 2;  // 16 MB
    unsigned short* chi = (unsigned short*)(ws + off); off += (size_t)K_ * D_ * 2;  // 8 MB

    hipLaunchKernelGGL(init_kernel, dim3(B_), dim3(256), 0, stream, x, resid, rr, rhi);

    for (int h = 0; h < H_; ++h) {
        const float* E  = cb + (size_t)h * K_ * D_;
        float* eh = ee + (size_t)h * K_;
        hipLaunchKernelGGL(cbconv_kernel, dim3(K_), dim3(256), 0, stream, E, chi, eh);
        hipLaunchKernelGGL(score_mfma_kernel, dim3((K_ / BN) * (B_ / BM)), dim3(256),
                           0, stream, chi, rhi, eh, pval, pidx);
        hipLaunchKernelGGL(update_kernel, dim3(B_ / 4), dim3(256), 0, stream,
                           resid, E, eh, pval, pidx, rr, codes, rhi, x, quant, h);
    }
}